// Round 8
// baseline (40.777 us; speedup 1.0000x reference)
//
#include <hip/hip_runtime.h>

// 3x3 VALID correlation on 4096x4096 fp32 -> 4094x4094 fp32, + bias.
// out[r][c] = sum_{kh,kw} X[r+kh][c+kw] * W[kh][kw] + bias (no kernel flip).
//
// Round-8: software-pipelined rolling window. 2048 blocks = exactly 8
// resident blocks/CU (one dispatch batch, no sequential batch latency).
// Each block: 512 cols x 16 rows, processed as 4 tiles of 4 rows with a
// 6-row register window; the next tile's 4 rows are prefetched BEFORE
// computing the current tile, so load latency is paid once per block
// instead of once per 4-row batch (rounds 5-7 were batch-latency-bound:
// three different designs all ~26.4us with VALU ~6%, HBM ~60% of ceiling).
// Lane owns 2 cols -> every load/store is a contiguous 512B wave access.
// Plain cached stores (NT stores gave 2.1x write amplification, round 3).
// Edges: clamp load addresses; garbage only feeds masked outputs.

constexpr int Hin = 4096;
constexpr int Win = 4096;
constexpr int OH  = 4094;
constexpr int OW  = 4094;

constexpr int TR = 4;    // rows per tile
constexpr int NT = 4;    // tiles per block
constexpr int BR = TR * NT;  // 16 rows per block
// block: 256 thr = 4 waves; wave 128 cols; block 512 cols x 16 rows
// grid: 8 col strips x 256 row blocks = 2048 blocks (8/CU, one batch)

__global__ __launch_bounds__(256, 8) void conv3x3_kernel(
    const float* __restrict__ X, const float* __restrict__ Wt,
    const float* __restrict__ B, float* __restrict__ Out)
{
    // XCD-chunked swizzle: 2048 blocks -> 256 consecutive b2 per XCD =
    // exactly one 512-col vertical strip per XCD (halo reuse in its L2).
    int nb = gridDim.x;
    int b  = blockIdx.x;
    int b2 = (b & 7) * (nb >> 3) + (b >> 3);

    int bx   = b2 >> 8;                 // 0..7   col strip (512 cols)
    int by   = b2 & 255;                // 0..255 row block (16 rows)
    int wave = threadIdx.x >> 6;
    int lane = threadIdx.x & 63;

    int c  = bx * 512 + wave * 128 + 2 * lane;   // out col base (even)
    int r0 = by * BR;

    // second window [c+2, c+4); clamp for the very last lane (c = 4094)
    int v1c = (c + 2 <= Win - 2) ? (c + 2) : (Win - 2);

    float w[9];
#pragma unroll
    for (int i = 0; i < 9; ++i) w[i] = Wt[i];
    const float bias = B[0];

    // ---- prologue: load 6-row window (12 coalesced float2 loads) ----
    float2 w0[6], w1[6];
#pragma unroll
    for (int j = 0; j < 6; ++j) {
        int rr = r0 + j;
        if (rr > Hin - 1) rr = Hin - 1;          // feeds only masked rows
        const float* row = X + (size_t)rr * Win;
        w0[j] = *reinterpret_cast<const float2*>(row + c);
        w1[j] = *reinterpret_cast<const float2*>(row + v1c);
    }

#pragma unroll
    for (int t = 0; t < NT; ++t) {
        // ---- prefetch next tile's 4 rows before computing this tile ----
        float2 p0[TR], p1[TR];
        if (t < NT - 1) {
#pragma unroll
            for (int j = 0; j < TR; ++j) {
                int rr = r0 + t * TR + 6 + j;
                if (rr > Hin - 1) rr = Hin - 1;
                const float* row = X + (size_t)rr * Win;
                p0[j] = *reinterpret_cast<const float2*>(row + c);
                p1[j] = *reinterpret_cast<const float2*>(row + v1c);
            }
        }

        // ---- compute 4 output rows from the 6-row window ----
        float2 acc[TR];
#pragma unroll
        for (int i = 0; i < TR; ++i) { acc[i].x = bias; acc[i].y = bias; }

#pragma unroll
        for (int i = 0; i < TR; ++i) {
#pragma unroll
            for (int kh = 0; kh < 3; ++kh) {
                int ir = i + kh;
                float q0 = w[kh * 3 + 0], q1 = w[kh * 3 + 1], q2 = w[kh * 3 + 2];
                acc[i].x = fmaf(w0[ir].x, q0, acc[i].x);
                acc[i].x = fmaf(w0[ir].y, q1, acc[i].x);
                acc[i].x = fmaf(w1[ir].x, q2, acc[i].x);
                acc[i].y = fmaf(w0[ir].y, q0, acc[i].y);
                acc[i].y = fmaf(w1[ir].x, q1, acc[i].y);
                acc[i].y = fmaf(w1[ir].y, q2, acc[i].y);
            }
        }

        // ---- coalesced float2 stores (8B aligned: c even) ----
        if (c < OW) {                            // masks only the c=4094 lane
#pragma unroll
            for (int i = 0; i < TR; ++i) {
                int orow = r0 + t * TR + i;
                if (orow < OH) {
                    *reinterpret_cast<float2*>(Out + (size_t)orow * OW + c) = acc[i];
                }
            }
        }

        // ---- shift window: keep last 2 rows, append prefetched 4 ----
        if (t < NT - 1) {
            w0[0] = w0[4]; w0[1] = w0[5];
            w1[0] = w1[4]; w1[1] = w1[5];
#pragma unroll
            for (int j = 0; j < TR; ++j) { w0[2 + j] = p0[j]; w1[2 + j] = p1[j]; }
        }
    }
}

extern "C" void kernel_launch(void* const* d_in, const int* in_sizes, int n_in,
                              void* d_out, int out_size, void* d_ws, size_t ws_size,
                              hipStream_t stream) {
    const float* X  = (const float*)d_in[0];
    const float* Wt = (const float*)d_in[1];
    const float* B  = (const float*)d_in[2];
    float* Out      = (float*)d_out;

    int blocks = 8 * 256;   // 2048, divisible by 8; 8 blocks/CU resident
    conv3x3_kernel<<<blocks, 256, 0, stream>>>(X, Wt, B, Out);
}